// Round 1
// baseline (1717.822 us; speedup 1.0000x reference)
//
#include <hip/hip_runtime.h>
#include <hip/hip_bf16.h>

// HiPPO-LegT LTI scan: c_t = dA c_{t-1} + dB u_t, out = all c_t. N=256, L=4096, B=64.
// Chunked parallel scan, T=64: powers -> chunk finals (conv) -> serial carry scan ->
// parallel per-chunk recurrence writing all outputs. All fp32 math except dA^64,
// which is split fp16 hi/lo (~22 mantissa bits) to fit hi in LDS.

#define N 256
#define LSEQ 4096
#define BATCH 64
#define TCH 64          // chunk length
#define NCH 64          // number of chunks (LSEQ/TCH)

struct __align__(8) h4v { _Float16 a, b, c, d; };

// ---- K[0] = dB ----
__global__ void init_k0(const float* __restrict__ dB, float* __restrict__ K) {
    K[threadIdx.x] = dB[threadIdx.x];
}

// ---- one doubling step: dst = src @ src (src = dA^m -> dst = dA^2m),
//      K[m+j] = src @ K[j] for j<m. Block = output row i, thread = col j. ----
__global__ __launch_bounds__(256) void pow_double(const float* __restrict__ src,
                                                  float* __restrict__ dst,
                                                  float* __restrict__ K, int m) {
    int i = blockIdx.x;
    int j = threadIdx.x;
    float accW = 0.f, accK = 0.f;
    for (int k = 0; k < N; ++k) {
        float a = src[i * N + k];            // wave-uniform
        accW += a * src[k * N + j];          // coalesced over j
        if (j < m) accK += a * K[j * N + k];
    }
    dst[i * N + j] = accW;
    if (j < m) K[(m + j) * N + i] = accK;
}

// ---- prep: Mh = fp16(M) row-major (for LDS), loT = fp16(M - Mh) transposed,
//      dAT = dA transposed (for coalesced reads in phase_c). M = dA^64. ----
__global__ __launch_bounds__(256) void prep(const float* __restrict__ M,
                                            const float* __restrict__ dA,
                                            _Float16* __restrict__ Mh,
                                            _Float16* __restrict__ loT,
                                            float* __restrict__ dAT) {
    int i = blockIdx.x, j = threadIdx.x;
    float m = M[i * N + j];
    _Float16 h = (_Float16)m;
    Mh[i * N + j] = h;
    loT[j * N + i] = (_Float16)(m - (float)h);
    dAT[j * N + i] = dA[i * N + j];
}

// ---- chunk-final states with zero init: f[k][b][i] = sum_p K[p][i]*u[kT+63-p][b] ----
__global__ __launch_bounds__(256) void finals(const float* __restrict__ K,
                                              const float* __restrict__ u,
                                              float* __restrict__ f) {
    int k = blockIdx.x, b = blockIdx.y, i = threadIdx.x;
    float acc = 0.f;
    int ubase = (k * TCH + 63) * BATCH + b;
    #pragma unroll 8
    for (int p = 0; p < TCH; ++p)
        acc += K[p * N + i] * u[ubase - p * BATCH];
    f[(k * BATCH + b) * N + i] = acc;
}

// ---- serial carry scan: s_{k+1} = M s_k + f_k ; carr[k] = s_k (state entering chunk k).
//      M as fp16 hi (LDS, XOR-swizzled quads) + fp16 lo (global, transposed). ----
__global__ __launch_bounds__(256) void carry_scan(const _Float16* __restrict__ Mh,
                                                  const _Float16* __restrict__ loT,
                                                  const float* __restrict__ f,
                                                  float* __restrict__ carr) {
    int b = blockIdx.x, tid = threadIdx.x;
    __shared__ __align__(16) _Float16 MhL[N * N];   // 128 KiB
    __shared__ __align__(16) float sbuf[N];
    // stage hi into LDS with per-row quad XOR swizzle (kills same-bank row reads)
    for (int e = tid; e < N * N; e += 256) {
        int ir = e >> 8, c = e & 255, q = c >> 2, r = c & 3;
        MhL[(ir << 8) + (((q ^ (ir & 31)) << 2) | r)] = Mh[e];
    }
    sbuf[tid] = 0.f;
    __syncthreads();
    int rowbase = tid << 8;
    int xm = tid & 31;
    for (int k = 0; k < NCH; ++k) {
        carr[(k * BATCH + b) * N + tid] = sbuf[tid];
        if (k == NCH - 1) break;
        float acc = f[(k * BATCH + b) * N + tid];
        #pragma unroll 4
        for (int q = 0; q < 64; ++q) {
            h4v hv = *(const h4v*)&MhL[rowbase + ((q ^ xm) << 2)];
            float4 sv = *(const float4*)&sbuf[q << 2];         // wave-broadcast
            float l0 = (float)loT[(q * 4 + 0) * N + tid];      // coalesced
            float l1 = (float)loT[(q * 4 + 1) * N + tid];
            float l2 = (float)loT[(q * 4 + 2) * N + tid];
            float l3 = (float)loT[(q * 4 + 3) * N + tid];
            acc += ((float)hv.a + l0) * sv.x + ((float)hv.b + l1) * sv.y
                 + ((float)hv.c + l2) * sv.z + ((float)hv.d + l3) * sv.w;
        }
        __syncthreads();
        sbuf[tid] = acc;
        __syncthreads();
    }
}

// ---- main: per (chunk, 16-batch group): 64-step fp32 recurrence from carry.
//      c-state in LDS (broadcast reads). dA read transposed (coalesced).
//      Thread tile 4i x 8b, j split in halves across wave pairs, LDS reduce. ----
__global__ __launch_bounds__(256) void phase_c(const float* __restrict__ u,
                                               const float* __restrict__ dAT,
                                               const float* __restrict__ dB,
                                               const float* __restrict__ carr,
                                               float* __restrict__ out) {
    int k = blockIdx.x;
    int b_base = blockIdx.y * 16;
    int tid = threadIdx.x;
    int lane = tid & 63;
    int w = tid >> 6;     // wave 0..3
    int jh = w >> 1;      // j-half 0..1
    int bg = w & 1;       // batch-octet 0..1
    __shared__ __align__(16) float cbuf[16 * N];        // 16 KiB  [b_local][j]
    __shared__ __align__(16) float part[2][16][N];      // 32 KiB

    for (int e = tid; e < 16 * N; e += 256)
        cbuf[e] = carr[k * (BATCH * N) + b_base * N + e];
    float dBr = dB[tid];  // final-phase i == tid
    __syncthreads();

    const float* uptr = u + b_base;
    for (int dt = 0; dt < TCH; ++dt) {
        int t = k * TCH + dt;
        float acc[4][8];
        #pragma unroll
        for (int q = 0; q < 4; ++q)
            #pragma unroll
            for (int bb = 0; bb < 8; ++bb) acc[q][bb] = 0.f;

        int j0base = jh * 128;
        #pragma unroll 4
        for (int jj = 0; jj < 32; ++jj) {
            int j0 = j0base + jj * 4;
            float av[4][4];
            #pragma unroll
            for (int jr = 0; jr < 4; ++jr)
                #pragma unroll
                for (int q = 0; q < 4; ++q)
                    av[jr][q] = dAT[(j0 + jr) * N + q * 64 + lane];  // coalesced
            #pragma unroll
            for (int bb = 0; bb < 8; ++bb) {
                float4 cv = *(const float4*)&cbuf[(bg * 8 + bb) * N + j0];  // broadcast
                #pragma unroll
                for (int q = 0; q < 4; ++q)
                    acc[q][bb] += av[0][q] * cv.x + av[1][q] * cv.y
                                + av[2][q] * cv.z + av[3][q] * cv.w;
            }
        }
        #pragma unroll
        for (int q = 0; q < 4; ++q)
            #pragma unroll
            for (int bb = 0; bb < 8; ++bb)
                part[jh][bg * 8 + bb][q * 64 + lane] = acc[q][bb];
        __syncthreads();

        int obase = t * (BATCH * N) + b_base * N;
        #pragma unroll
        for (int r = 0; r < 16; ++r) {
            float val = part[0][r][tid] + part[1][r][tid] + dBr * uptr[t * BATCH + r];
            cbuf[r * N + tid] = val;               // next-step state
            out[obase + r * N + tid] = val;        // coalesced 256B stores
        }
        __syncthreads();
    }
}

extern "C" void kernel_launch(void* const* d_in, const int* in_sizes, int n_in,
                              void* d_out, int out_size, void* d_ws, size_t ws_size,
                              hipStream_t stream) {
    (void)in_sizes; (void)n_in; (void)out_size; (void)ws_size;
    const float* u  = (const float*)d_in[0];
    const float* dA = (const float*)d_in[1];
    const float* dB = (const float*)d_in[2];
    float* out = (float*)d_out;
    char* ws = (char*)d_ws;

    // ws layout (bytes): total ~9.1 MB
    float*    Wa   = (float*)(ws + 0);          // 256 KB
    float*    Wb   = (float*)(ws + 262144);     // 256 KB
    float*    K    = (float*)(ws + 524288);     // 64 KB   K[p][i], p<64
    float*    f    = (float*)(ws + 589824);     // 4 MB    f[k][b][i]
    float*    carr = (float*)(ws + 4784128);    // 4 MB    carr[k][b][i]
    float*    dAT  = (float*)(ws + 8978432);    // 256 KB
    _Float16* Mh   = (_Float16*)(ws + 9240576); // 128 KB
    _Float16* loT  = (_Float16*)(ws + 9371648); // 128 KB

    init_k0<<<1, 256, 0, stream>>>(dB, K);
    pow_double<<<256, 256, 0, stream>>>(dA, Wa, K, 1);   // Wa = dA^2,  K[1]
    pow_double<<<256, 256, 0, stream>>>(Wa, Wb, K, 2);   // Wb = dA^4,  K[2..3]
    pow_double<<<256, 256, 0, stream>>>(Wb, Wa, K, 4);   // Wa = dA^8,  K[4..7]
    pow_double<<<256, 256, 0, stream>>>(Wa, Wb, K, 8);   // Wb = dA^16, K[8..15]
    pow_double<<<256, 256, 0, stream>>>(Wb, Wa, K, 16);  // Wa = dA^32, K[16..31]
    pow_double<<<256, 256, 0, stream>>>(Wa, Wb, K, 32);  // Wb = dA^64, K[32..63]
    prep<<<256, 256, 0, stream>>>(Wb, dA, Mh, loT, dAT);
    finals<<<dim3(NCH, BATCH), 256, 0, stream>>>(K, u, f);
    carry_scan<<<BATCH, 256, 0, stream>>>(Mh, loT, f, carr);
    phase_c<<<dim3(NCH, 4), 256, 0, stream>>>(u, dAT, dB, carr, out);
}

// Round 2
// 506.763 us; speedup vs baseline: 3.3898x; 3.3898x over previous
//
#include <hip/hip_runtime.h>
#include <hip/hip_bf16.h>
#include <stdint.h>

// HiPPO-LegT LTI scan: c_t = dA c_{t-1} + dB u_t, out = all c_t. N=256, L=4096, B=64.
// New structure: every output computed directly as
//   c[k*64+dt] = dA^{dt+1} . s_k  +  sum_{p<=dt} (dA^p dB) . u[k*64+dt-p]
// via split-bf16 MFMA (hi/lo, 3-MFMA products). Support kernels build the fp32 power
// stack dA^1..dA^64, K vectors, chunk finals, and a short fp32 carry scan.

#define N 256
#define LSEQ 4096
#define BATCH 64
#define TCH 64
#define NCH 64

using bf16x8 = __attribute__((ext_vector_type(8))) __bf16;
using f32x4  = __attribute__((ext_vector_type(4))) float;

__device__ __forceinline__ unsigned short f2bf(float f) {
  uint32_t x = __builtin_bit_cast(uint32_t, f);
  uint32_t r = x + 0x7fffu + ((x >> 16) & 1u);
  return (unsigned short)(r >> 16);
}
__device__ __forceinline__ float bf2f(unsigned short h) {
  uint32_t x = ((uint32_t)h) << 16;
  return __builtin_bit_cast(float, x);
}

// ======================= NEW PATH =======================

// prep0: bid<64 -> transpose u (L x B) into uT (B x L); bid>=64 -> copy dA into power
// slot 0 (dA^1) and write its bf16 hi/lo split.
__global__ __launch_bounds__(256) void prep0(const float* __restrict__ u,
                                             const float* __restrict__ dA,
                                             float* __restrict__ uT,
                                             float* __restrict__ Pw,
                                             unsigned short* __restrict__ Phi,
                                             unsigned short* __restrict__ Plo) {
  __shared__ float tile[64][65];
  int bid = blockIdx.x, tid = threadIdx.x;
  if (bid < 64) {
    int t0 = bid * 64;
    #pragma unroll
    for (int q = 0; q < 16; ++q) {
      int e = q * 256 + tid;
      int tt = e >> 6, b = e & 63;
      tile[b][tt] = u[(size_t)(t0 + tt) * 64 + b];       // coalesced read
    }
    __syncthreads();
    #pragma unroll
    for (int q = 0; q < 16; ++q) {
      int e = q * 256 + tid;
      int b = e >> 6, tt = e & 63;
      uT[(size_t)b * 4096 + t0 + tt] = tile[b][tt];      // coalesced write
    }
  } else {
    int base = (bid - 64) * 1024 + tid * 4;
    float4 v = *(const float4*)&dA[base];
    *(float4*)&Pw[base] = v;
    float vv[4] = {v.x, v.y, v.z, v.w};
    #pragma unroll
    for (int q = 0; q < 4; ++q) {
      unsigned short h = f2bf(vv[q]);
      Phi[base + q] = h;
      Plo[base + q] = f2bf(vv[q] - bf2f(h));
    }
  }
}

// pow_level: for q=1..half: P[half+q] = P[q] @ P[half] (slots are m-1). Writes fp32 +
// bf16 hi/lo split. Tiled 64x64 per block, grid (16 tiles, half).
__global__ __launch_bounds__(256) void pow_level(float* __restrict__ Pw,
                                                 unsigned short* __restrict__ Phi,
                                                 unsigned short* __restrict__ Plo,
                                                 int half) {
  __shared__ float As[64][17];
  __shared__ float Bs[16][64];
  int q = blockIdx.y + 1;
  const float* A = Pw + (size_t)(q - 1) * 65536;
  const float* B = Pw + (size_t)(half - 1) * 65536;
  size_t co = (size_t)(half + q - 1) * 65536;
  int bx = blockIdx.x;
  int gr0 = (bx >> 2) * 64, gc0 = (bx & 3) * 64;
  int tid = threadIdx.x;
  int ty = tid >> 4, tx = tid & 15;

  float acc[4][4];
  #pragma unroll
  for (int r = 0; r < 4; ++r)
    #pragma unroll
    for (int c = 0; c < 4; ++c) acc[r][c] = 0.f;

  for (int k0 = 0; k0 < 256; k0 += 16) {
    {
      int r = tid >> 2, c4 = (tid & 3) * 4;
      float4 va = *(const float4*)&A[(size_t)(gr0 + r) * 256 + k0 + c4];
      As[r][c4] = va.x; As[r][c4 + 1] = va.y; As[r][c4 + 2] = va.z; As[r][c4 + 3] = va.w;
      int kk = tid >> 4, c4b = (tid & 15) * 4;
      *(float4*)&Bs[kk][c4b] = *(const float4*)&B[(size_t)(k0 + kk) * 256 + gc0 + c4b];
    }
    __syncthreads();
    #pragma unroll
    for (int kk = 0; kk < 16; ++kk) {
      float a0 = As[ty * 4 + 0][kk], a1 = As[ty * 4 + 1][kk];
      float a2 = As[ty * 4 + 2][kk], a3 = As[ty * 4 + 3][kk];
      float b0 = Bs[kk][tx * 4 + 0], b1 = Bs[kk][tx * 4 + 1];
      float b2 = Bs[kk][tx * 4 + 2], b3 = Bs[kk][tx * 4 + 3];
      acc[0][0] += a0 * b0; acc[0][1] += a0 * b1; acc[0][2] += a0 * b2; acc[0][3] += a0 * b3;
      acc[1][0] += a1 * b0; acc[1][1] += a1 * b1; acc[1][2] += a1 * b2; acc[1][3] += a1 * b3;
      acc[2][0] += a2 * b0; acc[2][1] += a2 * b1; acc[2][2] += a2 * b2; acc[2][3] += a2 * b3;
      acc[3][0] += a3 * b0; acc[3][1] += a3 * b1; acc[3][2] += a3 * b2; acc[3][3] += a3 * b3;
    }
    __syncthreads();
  }
  #pragma unroll
  for (int r = 0; r < 4; ++r)
    #pragma unroll
    for (int c = 0; c < 4; ++c) {
      size_t idx = co + (size_t)(gr0 + ty * 4 + r) * 256 + gc0 + tx * 4 + c;
      float v = acc[r][c];
      Pw[idx] = v;
      unsigned short h = f2bf(v);
      Phi[idx] = h;
      Plo[idx] = f2bf(v - bf2f(h));
    }
}

// make_K: K[p] = dA^p dB (K[0]=dB). Block per p; wave-parallel row dots + shfl reduce.
__global__ __launch_bounds__(256) void make_K(const float* __restrict__ Pw,
                                              const float* __restrict__ dB,
                                              float* __restrict__ Kf,
                                              unsigned short* __restrict__ Khi,
                                              unsigned short* __restrict__ Klo) {
  int p = blockIdx.x, tid = threadIdx.x, lane = tid & 63, w = tid >> 6;
  if (p == 0) {
    float v = dB[tid];
    Kf[tid] = v;
    unsigned short h = f2bf(v);
    Khi[tid] = h;
    Klo[tid] = f2bf(v - bf2f(h));
    return;
  }
  const float* M = Pw + (size_t)(p - 1) * 65536;
  float d0 = dB[lane], d1 = dB[lane + 64], d2 = dB[lane + 128], d3 = dB[lane + 192];
  for (int ii = 0; ii < 64; ++ii) {
    int i = w * 64 + ii;
    const float* row = M + (size_t)i * 256;
    float acc = row[lane] * d0 + row[lane + 64] * d1 + row[lane + 128] * d2 + row[lane + 192] * d3;
    #pragma unroll
    for (int off = 32; off; off >>= 1) acc += __shfl_xor(acc, off, 64);
    if (lane == 0) {
      Kf[p * 256 + i] = acc;
      unsigned short h = f2bf(acc);
      Khi[p * 256 + i] = h;
      Klo[p * 256 + i] = f2bf(acc - bf2f(h));
    }
  }
}

// make_MT: MT[j][i] = (dA^64)[i][j]  (slot 63), for coalesced scan reads.
__global__ __launch_bounds__(256) void make_MT(const float* __restrict__ Pw,
                                               float* __restrict__ MT) {
  int j = blockIdx.x, i = threadIdx.x;
  MT[(size_t)j * 256 + i] = Pw[(size_t)63 * 65536 + (size_t)i * 256 + j];
}

// finals: f[k][b][i] = sum_p K[p][i]*u[k*64+63-p][b]  (zero-init chunk-end states)
__global__ __launch_bounds__(256) void finals(const float* __restrict__ K,
                                              const float* __restrict__ u,
                                              float* __restrict__ f) {
  int k = blockIdx.x, b = blockIdx.y, i = threadIdx.x;
  float acc = 0.f;
  int ubase = (k * TCH + 63) * BATCH + b;
  #pragma unroll 8
  for (int p = 0; p < TCH; ++p)
    acc += K[p * N + i] * u[ubase - p * BATCH];
  f[(k * BATCH + b) * N + i] = acc;
}

// scan: s_{k+1} = M s_k + f_k (fp32, M^T streamed from L2); writes s_k split hi/lo.
__global__ __launch_bounds__(512) void scan(const float* __restrict__ MT,
                                            const float* __restrict__ f,
                                            unsigned short* __restrict__ shi,
                                            unsigned short* __restrict__ slo) {
  __shared__ float sbuf[256];
  __shared__ float psum[256];
  int b = blockIdx.x, tid = threadIdx.x;
  int i = tid & 255, jh = tid >> 8;
  if (tid < 256) sbuf[i] = 0.f;
  __syncthreads();
  for (int k = 0; k < NCH; ++k) {
    if (jh == 0) {
      float v = sbuf[i];
      unsigned short h = f2bf(v);
      size_t o = (size_t)(k * BATCH + b) * 256 + i;
      shi[o] = h;
      slo[o] = f2bf(v - bf2f(h));
    }
    if (k == NCH - 1) break;
    float acc = 0.f;
    int j0 = jh * 128;
    #pragma unroll 8
    for (int j = 0; j < 128; ++j)
      acc += MT[(size_t)(j0 + j) * 256 + i] * sbuf[j0 + j];
    __syncthreads();
    if (jh == 1) psum[i] = acc;
    __syncthreads();
    if (jh == 0) sbuf[i] = acc + psum[i] + f[(size_t)(k * BATCH + b) * 256 + i];
    __syncthreads();
  }
}

// main_gemm: out[k*64+dt][b][i] = sum_j P[dt+1][i][j] s_k[b][j] + sum_{p<=dt} K[p][i] u[kT+dt-p][b]
// Split-bf16 MFMA (hi*hi + hi*lo + lo*hi). Block tile 128 kb-rows x 128 i-cols; 4 waves 2x2.
__global__ __launch_bounds__(256, 2) void main_gemm(const unsigned short* __restrict__ shi,
                                                    const unsigned short* __restrict__ slo,
                                                    const unsigned short* __restrict__ Phi,
                                                    const unsigned short* __restrict__ Plo,
                                                    const unsigned short* __restrict__ Khi,
                                                    const unsigned short* __restrict__ Klo,
                                                    const float* __restrict__ uT,
                                                    float* __restrict__ out) {
  __shared__ unsigned short Ah[128 * 40], Al[128 * 40], Bh[128 * 40], Bl[128 * 40];
  int dt = blockIdx.y;
  int x = blockIdx.x;
  int it = x >> 5, kbt = x & 31;
  int kb0 = kbt * 128, i0 = it * 128;
  int tid = threadIdx.x;
  int lane = tid & 63, wid = tid >> 6;
  int wr = wid >> 1, wc = wid & 1;

  f32x4 acc[4][4];
  #pragma unroll
  for (int mf = 0; mf < 4; ++mf)
    #pragma unroll
    for (int nf = 0; nf < 4; ++nf)
      #pragma unroll
      for (int r = 0; r < 4; ++r) acc[mf][nf][r] = 0.f;

  const unsigned short* PhiD = Phi + (size_t)dt * 65536;
  const unsigned short* PloD = Plo + (size_t)dt * 65536;
  int nkt = (dt >= 32) ? 10 : 9;

  for (int kt = 0; kt < nkt; ++kt) {
    int r = tid >> 1, h = tid & 1;
    if (kt < 8) {
      int co = kt * 32 + h * 16;
      const unsigned short* p1 = shi + (size_t)(kb0 + r) * 256 + co;
      const unsigned short* p2 = slo + (size_t)(kb0 + r) * 256 + co;
      const unsigned short* p3 = PhiD + (size_t)(i0 + r) * 256 + co;
      const unsigned short* p4 = PloD + (size_t)(i0 + r) * 256 + co;
      int lo_ = r * 40 + h * 16;
      *(uint4*)&Ah[lo_]     = *(const uint4*)p1;
      *(uint4*)&Ah[lo_ + 8] = *(const uint4*)(p1 + 8);
      *(uint4*)&Al[lo_]     = *(const uint4*)p2;
      *(uint4*)&Al[lo_ + 8] = *(const uint4*)(p2 + 8);
      *(uint4*)&Bh[lo_]     = *(const uint4*)p3;
      *(uint4*)&Bh[lo_ + 8] = *(const uint4*)(p3 + 8);
      *(uint4*)&Bl[lo_]     = *(const uint4*)p4;
      *(uint4*)&Bl[lo_ + 8] = *(const uint4*)(p4 + 8);
    } else {
      int p0 = (kt - 8) * 32;
      // A-side: masked shifted u (hi/lo split on the fly)
      int kk = (kb0 + r) >> 6, b = (kb0 + r) & 63;
      const float* ub2 = uT + (size_t)b * 4096 + kk * 64 + dt;
      #pragma unroll
      for (int qq = 0; qq < 16; ++qq) {
        int pp = h * 16 + qq;
        int sh = p0 + pp;
        float v = (sh <= dt) ? ub2[-sh] : 0.f;
        unsigned short hv = f2bf(v);
        Ah[r * 40 + pp] = hv;
        Al[r * 40 + pp] = f2bf(v - bf2f(hv));
      }
      // B-side: K rows (transpose into [n][k])
      int n = tid & 127, ph = tid >> 7;
      #pragma unroll
      for (int qq = 0; qq < 16; ++qq) {
        int pp = ph * 16 + qq;
        Bh[n * 40 + pp] = Khi[(p0 + pp) * 256 + i0 + n];
        Bl[n * 40 + pp] = Klo[(p0 + pp) * 256 + i0 + n];
      }
    }
    __syncthreads();

    int kseg = lane >> 4, fr = lane & 15;
    bf16x8 ah[4], al[4], bh[4], bl[4];
    #pragma unroll
    for (int mf = 0; mf < 4; ++mf) {
      int row = (wr * 64 + mf * 16 + fr) * 40 + kseg * 8;
      ah[mf] = *(const bf16x8*)&Ah[row];
      al[mf] = *(const bf16x8*)&Al[row];
    }
    #pragma unroll
    for (int nf = 0; nf < 4; ++nf) {
      int row = (wc * 64 + nf * 16 + fr) * 40 + kseg * 8;
      bh[nf] = *(const bf16x8*)&Bh[row];
      bl[nf] = *(const bf16x8*)&Bl[row];
    }
    #pragma unroll
    for (int mf = 0; mf < 4; ++mf)
      #pragma unroll
      for (int nf = 0; nf < 4; ++nf) {
        acc[mf][nf] = __builtin_amdgcn_mfma_f32_16x16x32_bf16(ah[mf], bh[nf], acc[mf][nf], 0, 0, 0);
        acc[mf][nf] = __builtin_amdgcn_mfma_f32_16x16x32_bf16(ah[mf], bl[nf], acc[mf][nf], 0, 0, 0);
        acc[mf][nf] = __builtin_amdgcn_mfma_f32_16x16x32_bf16(al[mf], bh[nf], acc[mf][nf], 0, 0, 0);
      }
    __syncthreads();
  }

  // epilogue: C[kb][i] -> out[(k*64+dt)*64 + b][i]
  int rg = lane >> 4, cl = lane & 15;
  #pragma unroll
  for (int mf = 0; mf < 4; ++mf) {
    int kbrow_base = kb0 + wr * 64 + mf * 16 + rg * 4;
    #pragma unroll
    for (int nf = 0; nf < 4; ++nf) {
      int i = i0 + wc * 64 + nf * 16 + cl;
      #pragma unroll
      for (int r = 0; r < 4; ++r) {
        int kbrow = kbrow_base + r;
        int k = kbrow >> 6, b = kbrow & 63;
        size_t t = (size_t)(k * 64 + dt);
        out[(t * 64 + b) * 256 + i] = acc[mf][nf][r];
      }
    }
  }
}

// ======================= OLD (fallback) PATH =======================

struct __align__(8) h4v { _Float16 a, b, c, d; };

__global__ void init_k0(const float* __restrict__ dB, float* __restrict__ K) {
  K[threadIdx.x] = dB[threadIdx.x];
}

__global__ __launch_bounds__(256) void pow_double(const float* __restrict__ src,
                                                  float* __restrict__ dst,
                                                  float* __restrict__ K, int m) {
  int i = blockIdx.x;
  int j = threadIdx.x;
  float accW = 0.f, accK = 0.f;
  for (int k = 0; k < N; ++k) {
    float a = src[i * N + k];
    accW += a * src[k * N + j];
    if (j < m) accK += a * K[j * N + k];
  }
  dst[i * N + j] = accW;
  if (j < m) K[(m + j) * N + i] = accK;
}

__global__ __launch_bounds__(256) void prep(const float* __restrict__ M,
                                            const float* __restrict__ dA,
                                            _Float16* __restrict__ Mh,
                                            _Float16* __restrict__ loT,
                                            float* __restrict__ dAT) {
  int i = blockIdx.x, j = threadIdx.x;
  float m = M[i * N + j];
  _Float16 h = (_Float16)m;
  Mh[i * N + j] = h;
  loT[j * N + i] = (_Float16)(m - (float)h);
  dAT[j * N + i] = dA[i * N + j];
}

__global__ __launch_bounds__(256) void carry_scan(const _Float16* __restrict__ Mh,
                                                  const _Float16* __restrict__ loT,
                                                  const float* __restrict__ f,
                                                  float* __restrict__ carr) {
  int b = blockIdx.x, tid = threadIdx.x;
  __shared__ __align__(16) _Float16 MhL[N * N];
  __shared__ __align__(16) float sbuf[N];
  for (int e = tid; e < N * N; e += 256) {
    int ir = e >> 8, c = e & 255, q = c >> 2, r = c & 3;
    MhL[(ir << 8) + (((q ^ (ir & 31)) << 2) | r)] = Mh[e];
  }
  sbuf[tid] = 0.f;
  __syncthreads();
  int rowbase = tid << 8;
  int xm = tid & 31;
  for (int k = 0; k < NCH; ++k) {
    carr[(k * BATCH + b) * N + tid] = sbuf[tid];
    if (k == NCH - 1) break;
    float acc = f[(k * BATCH + b) * N + tid];
    #pragma unroll 4
    for (int q = 0; q < 64; ++q) {
      h4v hv = *(const h4v*)&MhL[rowbase + ((q ^ xm) << 2)];
      float4 sv = *(const float4*)&sbuf[q << 2];
      float l0 = (float)loT[(q * 4 + 0) * N + tid];
      float l1 = (float)loT[(q * 4 + 1) * N + tid];
      float l2 = (float)loT[(q * 4 + 2) * N + tid];
      float l3 = (float)loT[(q * 4 + 3) * N + tid];
      acc += ((float)hv.a + l0) * sv.x + ((float)hv.b + l1) * sv.y
           + ((float)hv.c + l2) * sv.z + ((float)hv.d + l3) * sv.w;
    }
    __syncthreads();
    sbuf[tid] = acc;
    __syncthreads();
  }
}

__global__ __launch_bounds__(256) void phase_c(const float* __restrict__ u,
                                               const float* __restrict__ dAT,
                                               const float* __restrict__ dB,
                                               const float* __restrict__ carr,
                                               float* __restrict__ out) {
  int k = blockIdx.x;
  int b_base = blockIdx.y * 16;
  int tid = threadIdx.x;
  int lane = tid & 63;
  int w = tid >> 6;
  int jh = w >> 1;
  int bg = w & 1;
  __shared__ __align__(16) float cbuf[16 * N];
  __shared__ __align__(16) float part[2][16][N];

  for (int e = tid; e < 16 * N; e += 256)
    cbuf[e] = carr[k * (BATCH * N) + b_base * N + e];
  float dBr = dB[tid];
  __syncthreads();

  const float* uptr = u + b_base;
  for (int dtq = 0; dtq < TCH; ++dtq) {
    int t = k * TCH + dtq;
    float acc[4][8];
    #pragma unroll
    for (int q = 0; q < 4; ++q)
      #pragma unroll
      for (int bb = 0; bb < 8; ++bb) acc[q][bb] = 0.f;

    int j0base = jh * 128;
    #pragma unroll 4
    for (int jj = 0; jj < 32; ++jj) {
      int j0 = j0base + jj * 4;
      float av[4][4];
      #pragma unroll
      for (int jr = 0; jr < 4; ++jr)
        #pragma unroll
        for (int q = 0; q < 4; ++q)
          av[jr][q] = dAT[(j0 + jr) * N + q * 64 + lane];
      #pragma unroll
      for (int bb = 0; bb < 8; ++bb) {
        float4 cv = *(const float4*)&cbuf[(bg * 8 + bb) * N + j0];
        #pragma unroll
        for (int q = 0; q < 4; ++q)
          acc[q][bb] += av[0][q] * cv.x + av[1][q] * cv.y
                      + av[2][q] * cv.z + av[3][q] * cv.w;
      }
    }
    #pragma unroll
    for (int q = 0; q < 4; ++q)
      #pragma unroll
      for (int bb = 0; bb < 8; ++bb)
        part[jh][bg * 8 + bb][q * 64 + lane] = acc[q][bb];
    __syncthreads();

    int obase = t * (BATCH * N) + b_base * N;
    #pragma unroll
    for (int rr = 0; rr < 16; ++rr) {
      float val = part[0][rr][tid] + part[1][rr][tid] + dBr * uptr[t * BATCH + rr];
      cbuf[rr * N + tid] = val;
      out[obase + rr * N + tid] = val;
    }
    __syncthreads();
  }
}

// ======================= HOST =======================

extern "C" void kernel_launch(void* const* d_in, const int* in_sizes, int n_in,
                              void* d_out, int out_size, void* d_ws, size_t ws_size,
                              hipStream_t stream) {
  (void)in_sizes; (void)n_in; (void)out_size;
  const float* u  = (const float*)d_in[0];
  const float* dA = (const float*)d_in[1];
  const float* dB = (const float*)d_in[2];
  float* out = (float*)d_out;
  char* ws = (char*)d_ws;

  const size_t NEED = 43384832;
  if (ws_size >= NEED) {
    // new ws layout (bytes)
    float*          Pw  = (float*)(ws + 0);                  // 16 MB: dA^1..dA^64 (slot m-1)
    unsigned short* Phi = (unsigned short*)(ws + 16777216);  // 8 MB
    unsigned short* Plo = (unsigned short*)(ws + 25165824);  // 8 MB
    float*          Kf  = (float*)(ws + 33554432);           // 64 KB
    unsigned short* Khi = (unsigned short*)(ws + 33619968);  // 32 KB
    unsigned short* Klo = (unsigned short*)(ws + 33652736);  // 32 KB
    unsigned short* shi = (unsigned short*)(ws + 33685504);  // 2 MB
    unsigned short* slo = (unsigned short*)(ws + 35782656);  // 2 MB
    float*          f   = (float*)(ws + 37879808);           // 4 MB
    float*          uT  = (float*)(ws + 42074112);           // 1 MB
    float*          MT  = (float*)(ws + 43122688);           // 256 KB

    prep0<<<128, 256, 0, stream>>>(u, dA, uT, Pw, Phi, Plo);
    for (int half = 1; half <= 32; half <<= 1)
      pow_level<<<dim3(16, half), 256, 0, stream>>>(Pw, Phi, Plo, half);
    make_K<<<64, 256, 0, stream>>>(Pw, dB, Kf, Khi, Klo);
    make_MT<<<256, 256, 0, stream>>>(Pw, MT);
    finals<<<dim3(NCH, BATCH), 256, 0, stream>>>(Kf, u, f);
    scan<<<BATCH, 512, 0, stream>>>(MT, f, shi, slo);
    main_gemm<<<dim3(64, 64), 256, 0, stream>>>(shi, slo, Phi, Plo, Khi, Klo, uT, out);
  } else {
    // fallback: round-0 proven path (~9.5 MB ws)
    float*    Wa   = (float*)(ws + 0);
    float*    Wb   = (float*)(ws + 262144);
    float*    K    = (float*)(ws + 524288);
    float*    f    = (float*)(ws + 589824);
    float*    carr = (float*)(ws + 4784128);
    float*    dAT  = (float*)(ws + 8978432);
    _Float16* Mh   = (_Float16*)(ws + 9240576);
    _Float16* loT  = (_Float16*)(ws + 9371648);

    init_k0<<<1, 256, 0, stream>>>(dB, K);
    pow_double<<<256, 256, 0, stream>>>(dA, Wa, K, 1);
    pow_double<<<256, 256, 0, stream>>>(Wa, Wb, K, 2);
    pow_double<<<256, 256, 0, stream>>>(Wb, Wa, K, 4);
    pow_double<<<256, 256, 0, stream>>>(Wa, Wb, K, 8);
    pow_double<<<256, 256, 0, stream>>>(Wb, Wa, K, 16);
    pow_double<<<256, 256, 0, stream>>>(Wa, Wb, K, 32);
    prep<<<256, 256, 0, stream>>>(Wb, dA, Mh, loT, dAT);
    finals<<<dim3(NCH, BATCH), 256, 0, stream>>>(K, u, f);
    carry_scan<<<BATCH, 256, 0, stream>>>(Mh, loT, f, carr);
    phase_c<<<dim3(NCH, 4), 256, 0, stream>>>(u, dAT, dB, carr, out);
  }
}